// Round 8
// baseline (67.349 us; speedup 1.0000x reference)
//
#include <hip/hip_runtime.h>
#include <hip/hip_bf16.h>

#define NB 8
#define SEQ 2048
#define DIN 1024
#define DH 64

typedef __attribute__((ext_vector_type(8))) short bf16x8;
typedef __attribute__((ext_vector_type(4))) float f32x4;
typedef __attribute__((ext_vector_type(4))) unsigned int u32x4;

static __device__ __forceinline__ unsigned short f2bf(float f) {
    unsigned int u = __builtin_bit_cast(unsigned int, f);
    unsigned int r = (u + 0x7FFFu + ((u >> 16) & 1u)) >> 16;
    return (unsigned short)r;
}

static __device__ __forceinline__ unsigned int cvt_pk_bf16(float lo, float hi) {
    unsigned int d;
    asm volatile("v_cvt_pk_bf16_f32 %0, %1, %2" : "=v"(d) : "v"(lo), "v"(hi));
    return d;
}

// async global->LDS, 16B per lane, linear LDS dest (wave-uniform base + lane*16)
static __device__ __forceinline__ void gll16(const void* g, void* l) {
    __builtin_amdgcn_global_load_lds((const __attribute__((address_space(1))) unsigned int*)g,
                                     (__attribute__((address_space(3))) unsigned int*)l, 16, 0, 0);
}

#define WAITVM(N) asm volatile("s_waitcnt vmcnt(" #N ")" ::: "memory")

// ---------------- prep: W3T[col3][k] = bf16(W[k][col])  (col-major, 16B-contiguous in k)
__global__ __launch_bounds__(256) void prep_kernel(
    const float* __restrict__ Wq, const float* __restrict__ Wk, const float* __restrict__ Wv,
    unsigned short* __restrict__ W3T)
{
    int j = blockIdx.x * 256 + threadIdx.x;     // 0 .. 196607
    int mat = j >> 16;
    int rem = j & 65535;
    int k = rem >> 6;
    int c = rem & 63;
    const float* W = (mat == 0) ? Wq : ((mat == 1) ? Wk : Wv);
    float v = W[rem];                            // coalesced read
    W3T[(size_t)(mat * 64 + c) * 1024 + k] = f2bf(v);   // scattered 2B write (fire-and-forget)
}

// ---------------- QKV GEMM: fat tile 128x64, grid = 128 row-tiles x 3 col-tiles (ct == matrix).
// X staged f32 via global_load_lds (src-swizzled granules), W^T tile 8KB; 16 MFMA/wave/step.
__global__ __launch_bounds__(256) void qkv_kernel(
    const float* __restrict__ X, const unsigned short* __restrict__ W3T,
    const float* __restrict__ bq, const float* __restrict__ bk, const float* __restrict__ bv,
    unsigned short* __restrict__ Qb, unsigned short* __restrict__ Kb, unsigned short* __restrict__ Vt)
{
    __shared__ __align__(16) unsigned char Xa[2][32768];   // [128 rows][256B f32], 32B-granule swz
    __shared__ __align__(16) unsigned char Wt[2][8192];    // [64 cols][128B k], 16B-granule swz

    const int tid = threadIdx.x;
    const int w   = tid >> 6;
    const int l15 = tid & 15;
    const int lq  = (tid >> 4) & 3;
    const int wm  = w >> 1;        // row-half (64 rows)
    const int wn  = w & 1;         // col-half (32 cols)

    int bid = blockIdx.x;
    int sw = (bid & 7) * 48 + (bid >> 3);      // XCD-cluster: 48 consecutive per XCD
    const int rt = sw / 3;                     // row-tile (128 rows)
    const int ct = sw % 3;                     // col-tile == matrix {Q,K,V}

    const char* Xgb = (const char*)(X + (size_t)rt * 128 * DIN);
    const char* Wgb = (const char*)W3T + (size_t)ct * 64 * 2048;

    // X staging map: 8 issues x 256 thr x 16B = 32 KB; LDS byte b -> row=b>>8, granule G=(b>>5)&7, half h=(b>>4)&1
    int xr[8], xsrc[8];
    #pragma unroll
    for (int i = 0; i < 8; ++i) {
        int b = (i * 256 + tid) * 16;
        int r = b >> 8;
        int G = (b >> 5) & 7;
        int h = (b >> 4) & 1;
        xr[i] = b;
        xsrc[i] = r * 4096 + ((G ^ (r & 7)) << 5) + (h << 4);
    }
    // W staging map: 2 issues; LDS byte b -> col=b>>7, granule G=(b>>4)&7
    int wr[2], wsrc[2];
    #pragma unroll
    for (int i = 0; i < 2; ++i) {
        int b = (i * 256 + tid) * 16;
        int col = b >> 7;
        int G = (b >> 4) & 7;
        wr[i] = b;
        wsrc[i] = col * 2048 + ((G ^ (col & 7)) << 4);
    }

    f32x4 acc[4][2] = {};

    // prologue: issue tile 0
    #pragma unroll
    for (int i = 0; i < 8; ++i) gll16(Xgb + (size_t)xsrc[i], &Xa[0][xr[i]]);
    #pragma unroll
    for (int i = 0; i < 2; ++i) gll16(Wgb + (size_t)wsrc[i], &Wt[0][wr[i]]);

    #pragma unroll
    for (int t = 0; t < 16; ++t) {
        WAITVM(0);                       // L(t) landed (overlapped with compute(t-1))
        __builtin_amdgcn_s_barrier();    // all waves' portions visible; buf (t+1)&1 free
        __builtin_amdgcn_sched_barrier(0);

        if (t + 1 < 16) {
            #pragma unroll
            for (int i = 0; i < 8; ++i)
                gll16(Xgb + (size_t)xsrc[i] + (t + 1) * 256, &Xa[(t + 1) & 1][xr[i]]);
            #pragma unroll
            for (int i = 0; i < 2; ++i)
                gll16(Wgb + (size_t)wsrc[i] + (t + 1) * 128, &Wt[(t + 1) & 1][wr[i]]);
        }

        const unsigned char* xb = Xa[t & 1];
        const unsigned char* wb = Wt[t & 1];

        // A-frags: 4 m-tiles x 2 kk, f32 -> bf16 via cvt_pk
        bf16x8 a[4][2];
        #pragma unroll
        for (int m = 0; m < 4; ++m) {
            int r = wm * 64 + m * 16 + l15;
            const unsigned char* rp = xb + r * 256;
            #pragma unroll
            for (int kk = 0; kk < 2; ++kk) {
                int g = (kk * 4 + lq) ^ (r & 7);
                f32x4 f0 = *(const f32x4*)(rp + g * 32);
                f32x4 f1 = *(const f32x4*)(rp + g * 32 + 16);
                u32x4 pk;
                pk[0] = cvt_pk_bf16(f0[0], f0[1]);
                pk[1] = cvt_pk_bf16(f0[2], f0[3]);
                pk[2] = cvt_pk_bf16(f1[0], f1[1]);
                pk[3] = cvt_pk_bf16(f1[2], f1[3]);
                a[m][kk] = __builtin_bit_cast(bf16x8, pk);
            }
        }
        // B-frags: 2 n-tiles x 2 kk
        bf16x8 bf[2][2];
        #pragma unroll
        for (int n = 0; n < 2; ++n) {
            int col = wn * 32 + n * 16 + l15;
            #pragma unroll
            for (int kk = 0; kk < 2; ++kk)
                bf[n][kk] = *(const bf16x8*)(wb + col * 128 + (((kk * 4 + lq) ^ (col & 7)) << 4));
        }
        #pragma unroll
        for (int kk = 0; kk < 2; ++kk)
            #pragma unroll
            for (int m = 0; m < 4; ++m)
                #pragma unroll
                for (int n = 0; n < 2; ++n)
                    acc[m][n] = __builtin_amdgcn_mfma_f32_16x16x32_bf16(a[m][kk], bf[n][kk], acc[m][n], 0, 0, 0);
    }

    // epilogue: this block writes only matrix ct
    const float* bvec = (ct == 0) ? bq : ((ct == 1) ? bk : bv);
    #pragma unroll
    for (int n = 0; n < 2; ++n) {
        int c = wn * 32 + n * 16 + l15;
        float badd = bvec[c];
        #pragma unroll
        for (int m = 0; m < 4; ++m) {
            #pragma unroll
            for (int reg = 0; reg < 4; ++reg) {
                int row = rt * 128 + wm * 64 + m * 16 + lq * 4 + reg;
                unsigned short v16 = f2bf(acc[m][n][reg] + badd);
                if (ct == 0)      Qb[(size_t)row * DH + c] = v16;
                else if (ct == 1) Kb[(size_t)row * DH + c] = v16;
                else {
                    int bb = row >> 11, ss = row & 2047;
                    Vt[((size_t)(bb * DH + c)) * SEQ + ss] = v16;
                }
            }
        }
    }
}

// ---------------- flash attention (fixed-max), 4-way key split, counted-vmcnt pipeline. (unchanged r7)
#define AKT 64
#define ANT 8
#define PP 36

__global__ __launch_bounds__(256) void attn_kernel(
    const unsigned short* __restrict__ Qb, const unsigned short* __restrict__ Kb,
    const unsigned short* __restrict__ Vt, const int* __restrict__ mask,
    float* __restrict__ Opart, float* __restrict__ lpart)
{
    __shared__ __align__(16) unsigned char Ksm[3][8192];   // [64 keys][64 d] bf16, src-swizzled
    __shared__ __align__(16) unsigned char Vsm[3][8192];   // [64 d][64 keys] bf16, src-swizzled
    __shared__ short ps[4][32][PP];
    __shared__ float sml[4][32];

    const int tid = threadIdx.x;
    const int w   = tid >> 6;
    const int l15 = tid & 15;
    const int lq  = (tid >> 4) & 3;
    const int wm  = w >> 1;
    const int wn  = w & 1;

    int bid = blockIdx.x;
    int sbid = (bid & 7) * 128 + (bid >> 3);   // one batch per XCD
    const int b   = sbid >> 7;
    const int qt  = (sbid >> 2) & 31;
    const int kq  = sbid & 3;
    const int q0  = qt * 64;
    const int kb0 = kq * 512;

    bf16x8 aq[2][2];
    #pragma unroll
    for (int m = 0; m < 2; ++m)
        #pragma unroll
        for (int kk = 0; kk < 2; ++kk)
            aq[m][kk] = *(const bf16x8*)(Qb + ((size_t)(b * SEQ + q0 + wm * 32 + m * 16 + l15)) * DH + kk * 32 + lq * 8);

    int mk[ANT][2];
    #pragma unroll
    for (int t = 0; t < ANT; ++t) {
        mk[t][0] = mask[b * SEQ + kb0 + t * AKT + wn * 32 + l15];
        mk[t][1] = mask[b * SEQ + kb0 + t * AKT + wn * 32 + 16 + l15];
    }
    WAITVM(0);

    const char* Kg = (const char*)Kb + (size_t)(b * SEQ + kb0) * DH * 2;
    const char* Vg = (const char*)Vt + ((size_t)(b * DH) * SEQ + kb0) * 2;

    int slds[2], ksrc[2], vsrc[2];
    #pragma unroll
    for (int i = 0; i < 2; ++i) {
        int bb = i * 4096 + tid * 16;
        int row = bb >> 7;
        int g = (bb >> 4) & 7;
        int gs = g ^ (row & 7);
        slds[i] = bb;
        ksrc[i] = row * 128 + gs * 16;
        vsrc[i] = row * 4096 + gs * 16;
    }

    f32x4 o[2][4];
    #pragma unroll
    for (int m = 0; m < 2; ++m)
        #pragma unroll
        for (int n = 0; n < 4; ++n) o[m][n] = f32x4{0, 0, 0, 0};
    float lr[2][4] = {};
    const float rscale = 0.022097086912079612f;  // 1/sqrt(2048)

    #pragma unroll
    for (int i = 0; i < 2; ++i) gll16(Kg + (size_t)ksrc[i], &Ksm[0][slds[i]]);
    #pragma unroll
    for (int i = 0; i < 2; ++i) gll16(Vg + (size_t)vsrc[i], &Vsm[0][slds[i]]);
    #pragma unroll
    for (int i = 0; i < 2; ++i) gll16(Kg + (size_t)8192 + ksrc[i], &Ksm[1][slds[i]]);
    #pragma unroll
    for (int i = 0; i < 2; ++i) gll16(Vg + (size_t)128 + vsrc[i], &Vsm[1][slds[i]]);

    #pragma unroll
    for (int t = 0; t < ANT; ++t) {
        if (t < ANT - 1) { WAITVM(4); } else { WAITVM(0); }
        __builtin_amdgcn_s_barrier();
        __builtin_amdgcn_sched_barrier(0);

        if (t + 2 < ANT) {
            int bi = (t + 2) % 3;
            #pragma unroll
            for (int i = 0; i < 2; ++i) gll16(Kg + (size_t)(t + 2) * 8192 + ksrc[i], &Ksm[bi][slds[i]]);
            #pragma unroll
            for (int i = 0; i < 2; ++i) gll16(Vg + (size_t)(t + 2) * 128 + vsrc[i], &Vsm[bi][slds[i]]);
        }

        const unsigned char* kt  = Ksm[t % 3];
        const unsigned char* vt2 = Vsm[t % 3];

        bf16x8 bkf[2][2];
        #pragma unroll
        for (int n = 0; n < 2; ++n)
            #pragma unroll
            for (int kk = 0; kk < 2; ++kk) {
                int row = wn * 32 + n * 16 + l15;
                bkf[n][kk] = *(const bf16x8*)(kt + row * 128 + ((4 * kk + lq) ^ (row & 7)) * 16);
            }
        f32x4 s[2][2];
        #pragma unroll
        for (int m = 0; m < 2; ++m)
            #pragma unroll
            for (int n = 0; n < 2; ++n) s[m][n] = f32x4{0, 0, 0, 0};
        #pragma unroll
        for (int kk = 0; kk < 2; ++kk)
            #pragma unroll
            for (int m = 0; m < 2; ++m)
                #pragma unroll
                for (int n = 0; n < 2; ++n)
                    s[m][n] = __builtin_amdgcn_mfma_f32_16x16x32_bf16(aq[m][kk], bkf[n][kk], s[m][n], 0, 0, 0);

        float bb0 = mk[t][0] ? -1e30f : 0.0f;
        float bb1 = mk[t][1] ? -1e30f : 0.0f;
        #pragma unroll
        for (int m = 0; m < 2; ++m)
            #pragma unroll
            for (int n = 0; n < 2; ++n) {
                float bvv = n ? bb1 : bb0;
                #pragma unroll
                for (int r = 0; r < 4; ++r) {
                    float p = __expf(fmaf(s[m][n][r], rscale, bvv));
                    lr[m][r] += p;
                    ps[w][m * 16 + lq * 4 + r][n * 16 + l15] = (short)f2bf(p);
                }
            }

        bf16x8 pa[2];
        #pragma unroll
        for (int m = 0; m < 2; ++m)
            pa[m] = *(const bf16x8*)&ps[w][m * 16 + l15][lq * 8];
        bf16x8 bvf[4];
        #pragma unroll
        for (int n = 0; n < 4; ++n) {
            int row = n * 16 + l15;
            bvf[n] = *(const bf16x8*)(vt2 + row * 128 + ((4 * wn + lq) ^ (row & 7)) * 16);
        }
        #pragma unroll
        for (int m = 0; m < 2; ++m)
            #pragma unroll
            for (int n = 0; n < 4; ++n)
                o[m][n] = __builtin_amdgcn_mfma_f32_16x16x32_bf16(pa[m], bvf[n], o[m][n], 0, 0, 0);
    }

    #pragma unroll
    for (int off = 1; off < 16; off <<= 1)
        #pragma unroll
        for (int m = 0; m < 2; ++m)
            #pragma unroll
            for (int r = 0; r < 4; ++r) lr[m][r] += __shfl_xor(lr[m][r], off);
    if (l15 == 0) {
        #pragma unroll
        for (int m = 0; m < 2; ++m)
            #pragma unroll
            for (int r = 0; r < 4; ++r) sml[w][m * 16 + lq * 4 + r] = lr[m][r];
    }
    __syncthreads();

    float (*mg)[32][64] = reinterpret_cast<float (*)[32][64]>(&Ksm[0][0]);
    if (wn == 1) {
        #pragma unroll
        for (int m = 0; m < 2; ++m)
            #pragma unroll
            for (int n = 0; n < 4; ++n)
                #pragma unroll
                for (int r = 0; r < 4; ++r)
                    mg[wm][m * 16 + lq * 4 + r][n * 16 + l15] = o[m][n][r];
    }
    __syncthreads();
    if (wn == 0) {
        #pragma unroll
        for (int m = 0; m < 2; ++m)
            #pragma unroll
            for (int n = 0; n < 4; ++n)
                #pragma unroll
                for (int r = 0; r < 4; ++r)
                    mg[wm][m * 16 + lq * 4 + r][n * 16 + l15] += o[m][n][r];
    }
    __syncthreads();

    {
        int qq = tid >> 2;
        int d0 = (tid & 3) * 16;
        float* dst = Opart + ((size_t)kq * (NB * SEQ) + b * SEQ + q0 + qq) * DH + d0;
        #pragma unroll
        for (int j = 0; j < 4; ++j)
            *(float4*)(dst + j * 4) = *(float4*)&mg[qq >> 5][qq & 31][d0 + j * 4];
    }
    if (tid < 64) {
        int wmi = tid >> 5;
        float lsum = sml[wmi * 2][tid & 31] + sml[wmi * 2 + 1][tid & 31];
        lpart[(size_t)kq * (NB * SEQ) + b * SEQ + q0 + tid] = lsum;
    }
}

// ---------------- merge: out = (sum_p Opart[p]) / (sum_p lpart[p])
__global__ __launch_bounds__(256) void merge_kernel(
    const float* __restrict__ Opart, const float* __restrict__ lpart,
    float* __restrict__ out)
{
    int bid = blockIdx.x;
    int sbid = (bid & 7) * 32 + (bid >> 3);
    int g = sbid * 256 + threadIdx.x;
    int q  = g >> 2;
    int d0 = (g & 3) * 16;

    float l = lpart[q] + lpart[16384 + q] + lpart[2 * 16384 + q] + lpart[3 * 16384 + q];
    float inv = 1.0f / l;

    const float* o0 = Opart + (size_t)q * DH + d0;
    #pragma unroll
    for (int j = 0; j < 4; ++j) {
        float4 a = *(const float4*)(o0 + j * 4);
        float4 b2 = *(const float4*)(o0 + (size_t)16384 * DH + j * 4);
        float4 c = *(const float4*)(o0 + (size_t)2 * 16384 * DH + j * 4);
        float4 d = *(const float4*)(o0 + (size_t)3 * 16384 * DH + j * 4);
        float4 r;
        r.x = (a.x + b2.x + c.x + d.x) * inv;
        r.y = (a.y + b2.y + c.y + d.y) * inv;
        r.z = (a.z + b2.z + c.z + d.z) * inv;
        r.w = (a.w + b2.w + c.w + d.w) * inv;
        *(float4*)(out + (size_t)q * DH + d0 + j * 4) = r;
    }
}

extern "C" void kernel_launch(void* const* d_in, const int* in_sizes, int n_in,
                              void* d_out, int out_size, void* d_ws, size_t ws_size,
                              hipStream_t stream) {
    const float* X    = (const float*)d_in[0];
    const int*   mask = (const int*)d_in[1];
    const float* Wq   = (const float*)d_in[2];
    const float* bq   = (const float*)d_in[3];
    const float* Wk   = (const float*)d_in[4];
    const float* bk   = (const float*)d_in[5];
    const float* Wv   = (const float*)d_in[6];
    const float* bv   = (const float*)d_in[7];
    float* out = (float*)d_out;

    char* ws = (char*)d_ws;
    unsigned short* Qb    = (unsigned short*)(ws);                 // 2 MiB
    unsigned short* Kb    = (unsigned short*)(ws + (2u << 20));    // 2 MiB
    unsigned short* Vt    = (unsigned short*)(ws + (4u << 20));    // 2 MiB
    unsigned short* W3T   = (unsigned short*)(ws + (6u << 20));    // 384 KiB
    float* Opart          = (float*)(ws + (8u << 20));             // 16 MiB
    float* lpart          = (float*)(ws + (24u << 20));            // 256 KiB

    prep_kernel<<<768, 256, 0, stream>>>(Wq, Wk, Wv, W3T);
    qkv_kernel<<<384, 256, 0, stream>>>(X, W3T, bq, bk, bv, Qb, Kb, Vt);
    attn_kernel<<<1024, 256, 0, stream>>>(Qb, Kb, Vt, mask, Opart, lpart);
    merge_kernel<<<256, 256, 0, stream>>>(Opart, lpart, out);
}